// Round 9
// baseline (2442.702 us; speedup 1.0000x reference)
//
#include <hip/hip_runtime.h>

#define VOCAB   32000
#define WORDVEC 256
#define HIDDEN  512
#define TSTEPS  256
#define NBATCH  16
#define NROWS   (TSTEPS*NBATCH)   // 4096
#define GATES   (4*HIDDEN)        // 2048
#define NVB     125               // 32000/256
#define NWG     32                // LSTM workgroups (32 x 16 hidden units)
#define NWGEMM  500               // persistent vocab workers (125 bn x 4)

typedef __attribute__((ext_vector_type(8))) short short8;
typedef __attribute__((ext_vector_type(4))) float f32x4;
typedef unsigned long long u64;

__device__ __forceinline__ unsigned short f2bf(float x){
    union { float f; unsigned int u; } v; v.f = x;
    unsigned int r = v.u + 0x7fffu + ((v.u >> 16) & 1u);
    return (unsigned short)(r >> 16);
}

// ---------------------------------------------------------------- K0a:
// W_vocab (fp32 [512][32000]) -> WvP: MFMA-B-fragment-linear bf16.
__global__ __launch_bounds__(256) void wv_pack(const float* __restrict__ Wv, unsigned short* __restrict__ WvP){
    __shared__ float s[64][65];
    int v0 = blockIdx.x * 64;     // 500 blocks
    int k0 = blockIdx.y * 64;     // 8 blocks
    int tid = threadIdx.x;
    for (int i = 0; i < 16; ++i){
        int lin = tid + i*256;
        int kk = lin >> 6, vv = lin & 63;
        s[kk][vv] = Wv[(long)(k0+kk)*VOCAB + v0 + vv];
    }
    __syncthreads();
    for (int i = 0; i < 2; ++i){
        int lr = tid + i*256;          // 0..511 lane-rows
        int f  = lr >> 6;              // vbl(0..3) x ktl(0..1)
        int vbl = f >> 1, ktl = f & 1;
        int L = lr & 63, q = L >> 4, ln = L & 15;
        short8 o;
        #pragma unroll
        for (int j = 0; j < 8; ++j)
            o[j] = (short)f2bf(s[ktl*32 + q*8 + j][vbl*16 + ln]);
        long vb = blockIdx.x*4 + vbl;
        long kt = blockIdx.y*2 + ktl;
        *(short8*)(WvP + ((vb*16 + kt)*64 + L)*8) = o;
    }
}

// ---------------------------------------------------------------- K0b:
// Wh (fp32 [512][2048]) -> Whp: per-WG MFMA-B-fragment-ordered bf16 image.
__global__ void whp_prep(const float* __restrict__ Wh, unsigned short* __restrict__ Whp){
    int w = blockIdx.x; int tid = threadIdx.x;   // 32 blocks x 256 thr
    for (int item = tid; item < 4096; item += 256){
        int f = item >> 6;          // 0..63
        int L = item & 63;
        int kt = f >> 2, nt = f & 3;
        int q = L >> 4, ln = L & 15;
        int col = nt*HIDDEN + w*16 + ln;   // gate nt, unit w*16+ln
        short8 vvec;
        for (int jj = 0; jj < 8; ++jj){
            int k = kt*32 + q*8 + jj;
            vvec[jj] = (short)f2bf(Wh[(long)k*GATES + col]);
        }
        *(short8*)(Whp + ((long)w*4096 + item)*8) = vvec;
    }
}

// ---------------------------------------------------------------- K0c:
// h_0 into exchange buffer 0 as tagged pairs: u64 = {tag=0 | bf16 hi | bf16 lo}.
__global__ void hg_init(const float* __restrict__ h_init, u64* __restrict__ hx){
    int p = blockIdx.x*256 + threadIdx.x;   // 4096 pairs
    int fq = p >> 6;
    int j  = (p & 3) * 2;
    int u0 = (fq>>2)*32 + (fq&3)*8 + j;
    u64 pk = (u64)f2bf(h_init[u0]) | ((u64)f2bf(h_init[u0+1]) << 16);   // tag 0
    hx[p] = pk;
}

// ---------------------------------------------------------------- K1:
// xw[r=t*16+n][k] = b[k] + sum_d W_embed[cap_in[n][t]][d] * Wx[d][k]   (fp32)
__global__ __launch_bounds__(256) void embed_xw(const int* __restrict__ captions,
        const float* __restrict__ Wemb, const float* __restrict__ Wx,
        const float* __restrict__ b, float* __restrict__ xw){
    __shared__ float xs[8][WORDVEC];
    __shared__ int toks[8];
    int tid = threadIdx.x;
    int r0 = blockIdx.x * 8;
    if (tid < 8){
        int r = r0 + tid; int t = r >> 4, n = r & 15;
        toks[tid] = captions[n*257 + t];
    }
    __syncthreads();
    for (int i = 0; i < 8; ++i){
        int lin = tid + i*256;
        int ri = lin >> 8, d = lin & 255;
        xs[ri][d] = Wemb[(long)toks[ri]*WORDVEC + d];
    }
    __syncthreads();
    float4 b0 = *(const float4*)(b + tid*4);
    float4 b1 = *(const float4*)(b + 1024 + tid*4);
    float acc[8][8];
    for (int ri = 0; ri < 8; ++ri){
        acc[ri][0]=b0.x; acc[ri][1]=b0.y; acc[ri][2]=b0.z; acc[ri][3]=b0.w;
        acc[ri][4]=b1.x; acc[ri][5]=b1.y; acc[ri][6]=b1.z; acc[ri][7]=b1.w;
    }
    for (int d = 0; d < WORDVEC; ++d){
        float4 w0 = *(const float4*)(Wx + (long)d*GATES + tid*4);
        float4 w1 = *(const float4*)(Wx + (long)d*GATES + 1024 + tid*4);
        #pragma unroll
        for (int ri = 0; ri < 8; ++ri){
            float xv = xs[ri][d];
            acc[ri][0] += xv*w0.x; acc[ri][1] += xv*w0.y;
            acc[ri][2] += xv*w0.z; acc[ri][3] += xv*w0.w;
            acc[ri][4] += xv*w1.x; acc[ri][5] += xv*w1.y;
            acc[ri][6] += xv*w1.z; acc[ri][7] += xv*w1.w;
        }
    }
    for (int ri = 0; ri < 8; ++ri){
        float4 o0 = {acc[ri][0],acc[ri][1],acc[ri][2],acc[ri][3]};
        float4 o1 = {acc[ri][4],acc[ri][5],acc[ri][6],acc[ri][7]};
        *(float4*)(xw + (long)(r0+ri)*GATES + tid*4) = o0;
        *(float4*)(xw + (long)(r0+ri)*GATES + 1024 + tid*4) = o1;
    }
}

// ---------------------------------------------------------------- K2 (FUSED):
// blocks 0..31: LSTM producers (round-8 core, tagged-u64 hx exchange).
//   hsP history written t-major fragment-linear as packed u64 relaxed-agent
//   stores; every 4 steps: vmcnt(0) drain + atomicAdd(cnt[tb]) -> tile ready.
// blocks 32..531: persistent vocab workers. Worker wid: bn = wid%125 (fixed,
//   L2 affinity), tb = wid/125 + 4k (k=0..15, t-ordered). Poll cnt[tb]==32,
//   then fused GEMM + softmax partials. A-loads relaxed-atomic (LLC-direct).
__global__ __launch_bounds__(256) void fused_lstm_vocab(
        const float* __restrict__ xw, const unsigned short* __restrict__ Whp,
        u64* __restrict__ hx, u64* __restrict__ hsPq, int* __restrict__ cnt,
        const unsigned short* __restrict__ WvP, const float* __restrict__ bvoc,
        const int* __restrict__ captions, float* __restrict__ pmax,
        float* __restrict__ psum, float* __restrict__ tlog){
    __shared__ char smem[20480];
    int tid = threadIdx.x;
    int wv = tid >> 6;
    int L = tid & 63;
    int q = L >> 4, ln = L & 15;

    if (blockIdx.x < NWG){
        // ==================== LSTM producer ====================
        unsigned int* hstage = (unsigned int*)smem;                 // 16 KB
        float (*a_s)[16][16] = (float (*)[16][16])(smem + 16384);   // 4 KB
        int w = blockIdx.x;
        int s_idx = tid >> 4, jl = tid & 15;

        short8 bw[16];
        #pragma unroll
        for (int kt = 0; kt < 16; ++kt)
            bw[kt] = *(const short8*)(Whp + ((long)w*4096 + (kt*4+wv)*64 + L)*8);

        float c_r = 0.f;
        int fq_pub = (w>>1)*4 + (w&1)*2 + (jl>>3);
        int pubIdx = fq_pub*64 + s_idx*4 + ((jl>>1)&3);
        int kt_h = w >> 1;
        int q_h  = ((w & 1) << 1) | (jl >> 3);
        int jq   = (jl & 7) >> 2;       // 0/1 for storer threads

        for (int t = 0; t < TSTEPS; ++t){
            long xb = (long)(t*16 + s_idx)*GATES + w*16 + jl;
            float xg0 = xw[xb], xg1 = xw[xb+512], xg2 = xw[xb+1024], xg3 = xw[xb+1536];

            const u64* hr = hx + (t & 1)*4096;
            u64*       hw = hx + ((t+1) & 1)*4096;

            u64 v[16];
            #pragma unroll
            for (int i = 0; i < 16; ++i)
                v[i] = __hip_atomic_load(hr + tid + i*256, __ATOMIC_RELAXED, __HIP_MEMORY_SCOPE_AGENT);
            for (;;){
                u64 bad = 0;
                #pragma unroll
                for (int i = 0; i < 16; ++i) bad |= (v[i] >> 32) ^ (u64)(unsigned)t;
                if (!bad) break;
                #pragma unroll
                for (int i = 0; i < 16; ++i)
                    v[i] = __hip_atomic_load(hr + tid + i*256, __ATOMIC_RELAXED, __HIP_MEMORY_SCOPE_AGENT);
            }
            #pragma unroll
            for (int i = 0; i < 16; ++i) hstage[tid + i*256] = (unsigned)v[i];
            __syncthreads();   // S1

            f32x4 acc = {0.f,0.f,0.f,0.f};
            #pragma unroll
            for (int kt = 0; kt < 16; ++kt){
                short8 a = *(const short8*)((const unsigned short*)hstage + (kt*256 + q*64 + ln*4)*2);
                acc = __builtin_amdgcn_mfma_f32_16x16x32_bf16(a, bw[kt], acc, 0, 0, 0);
            }
            #pragma unroll
            for (int r = 0; r < 4; ++r) a_s[wv][q*4 + r][ln] = acc[r];
            __syncthreads();   // S2

            float ai = a_s[0][s_idx][jl] + xg0;
            float af = a_s[1][s_idx][jl] + xg1;
            float ao = a_s[2][s_idx][jl] + xg2;
            float ag = a_s[3][s_idx][jl] + xg3;
            float ig = 1.f/(1.f + __expf(-ai));
            float fg = 1.f/(1.f + __expf(-af));
            float og = 1.f/(1.f + __expf(-ao));
            float gg = 2.f/(1.f + __expf(-2.f*ag)) - 1.f;
            c_r = fg*c_r + ig*gg;
            float hv = og * (2.f/(1.f + __expf(-2.f*c_r)) - 1.f);
            unsigned short hb = f2bf(hv);

            // critical-path publish: pair {tag=t+1 | h[jl+1] | h[jl]}
            int hv32 = (int)hb;
            int other = __shfl(hv32, (L & ~1) | ((L & 1) ^ 1));
            if ((jl & 1) == 0){
                u64 pk = (u64)(unsigned short)hv32
                       | ((u64)(unsigned short)other << 16)
                       | ((u64)(unsigned)(t+1) << 32);
                __hip_atomic_store(hw + pubIdx, pk, __ATOMIC_RELAXED, __HIP_MEMORY_SCOPE_AGENT);
            }

            // hsP history publish: quad-pack, relaxed agent (t-major: rb == t)
            int b4 = L & ~3;
            u64 q0 = (unsigned short)__shfl(hv32, b4);
            u64 q1 = (unsigned short)__shfl(hv32, b4+1);
            u64 q2 = (unsigned short)__shfl(hv32, b4+2);
            u64 q3 = (unsigned short)__shfl(hv32, b4+3);
            if ((jl & 3) == 0){
                u64 pk2 = q0 | (q1 << 16) | (q2 << 32) | (q3 << 48);
                long hIdx = ((long)(t*16 + kt_h)*64 + q_h*16 + s_idx)*2 + jq;
                __hip_atomic_store(hsPq + hIdx, pk2, __ATOMIC_RELAXED, __HIP_MEMORY_SCOPE_AGENT);
            }
            if ((t & 3) == 3){
                __asm__ __volatile__("s_waitcnt vmcnt(0)" ::: "memory");
                __syncthreads();
                if (tid == 0) atomicAdd(cnt + (t >> 2)*32, 1);
            }
        }
    } else {
        // ==================== vocab consumer ====================
        int wid = blockIdx.x - NWG;    // 0..499
        int bn  = wid % 125;
        int r0  = wid / 125;           // 0..3
        int* tgt_s = (int*)smem;                       // 256 B
        float (*wmax_s)[64] = (float (*)[64])(smem + 256);    // 1 KB
        float (*wsum_s)[64] = (float (*)[64])(smem + 1280);   // 1 KB
        int colb = bn*256 + wv*64;
        const unsigned short* bB = WvP + ((long)(bn*16 + wv*4)*16)*512;

        for (int it = 0; it < 16; ++it){
            int bm = r0 + it*4;        // M-tile = t-chunk [bm*4, bm*4+4)
            if (tid == 0){
                const int* cp = cnt + bm*32;
                while (__hip_atomic_load(cp, __ATOMIC_RELAXED, __HIP_MEMORY_SCOPE_AGENT) < NWG)
                    __builtin_amdgcn_s_sleep(8);
            }
            __syncthreads();           // tile ready (also guards smem reuse)
            if (tid < 64){
                int rg = bm*64 + tid;  // r = t*16 + s
                tgt_s[tid] = captions[(rg & 15)*257 + (rg >> 4) + 1];
            }
            __syncthreads();

            f32x4 acc[4][4];
            #pragma unroll
            for (int mt=0;mt<4;++mt)
                #pragma unroll
                for (int nt=0;nt<4;++nt) acc[mt][nt] = (f32x4){0.f,0.f,0.f,0.f};

            #pragma unroll 2
            for (int kt = 0; kt < 16; ++kt){
                short8 a[4], bb[4];
                #pragma unroll
                for (int mt=0;mt<4;++mt){
                    long ab = ((long)((bm*4+mt)*16 + kt)*64 + L)*2;
                    union { u64 u[2]; short8 s; } c;
                    c.u[0] = __hip_atomic_load(hsPq + ab,     __ATOMIC_RELAXED, __HIP_MEMORY_SCOPE_AGENT);
                    c.u[1] = __hip_atomic_load(hsPq + ab + 1, __ATOMIC_RELAXED, __HIP_MEMORY_SCOPE_AGENT);
                    a[mt] = c.s;
                }
                #pragma unroll
                for (int nt=0;nt<4;++nt)
                    bb[nt] = *(const short8*)(bB + ((long)(nt*16 + kt)*64 + L)*8);
                #pragma unroll
                for (int mt=0;mt<4;++mt)
                    #pragma unroll
                    for (int nt=0;nt<4;++nt)
                        acc[mt][nt] = __builtin_amdgcn_mfma_f32_16x16x32_bf16(a[mt], bb[nt], acc[mt][nt], 0,0,0);
            }
            float bv[4];
            #pragma unroll
            for (int nt=0;nt<4;++nt) bv[nt] = bvoc[colb + nt*16 + ln];
            #pragma unroll
            for (int mt=0;mt<4;++mt) for (int nt=0;nt<4;++nt) for (int r=0;r<4;++r)
                acc[mt][nt][r] += bv[nt];
            // target-logit grab
            #pragma unroll
            for (int mt=0;mt<4;++mt) for (int r=0;r<4;++r){
                int rl = mt*16 + q*4 + r;
                int tg = tgt_s[rl] - colb;
                if (tg >= 0 && tg < 64){
                    int nt = tg >> 4;
                    if ((tg & 15) == ln) tlog[bm*64 + rl] = acc[mt][nt][r];
                }
            }
            // per-row max & sumexp over this block's 256 cols
            #pragma unroll
            for (int mt=0;mt<4;++mt){
                #pragma unroll
                for (int r=0;r<4;++r){
                    float m = fmaxf(fmaxf(acc[mt][0][r],acc[mt][1][r]), fmaxf(acc[mt][2][r],acc[mt][3][r]));
                    for (int d=1; d<16; d<<=1) m = fmaxf(m, __shfl_xor(m, d, 16));
                    float s = __expf(acc[mt][0][r]-m) + __expf(acc[mt][1][r]-m)
                            + __expf(acc[mt][2][r]-m) + __expf(acc[mt][3][r]-m);
                    for (int d=1; d<16; d<<=1) s += __shfl_xor(s, d, 16);
                    if (ln == 0){ int rl = mt*16 + q*4 + r; wmax_s[wv][rl] = m; wsum_s[wv][rl] = s; }
                }
            }
            __syncthreads();
            if (tid < 64){
                float M = fmaxf(fmaxf(wmax_s[0][tid],wmax_s[1][tid]), fmaxf(wmax_s[2][tid],wmax_s[3][tid]));
                float S = 0.f;
                for (int ww=0; ww<4; ++ww) S += wsum_s[ww][tid]*__expf(wmax_s[ww][tid]-M);
                pmax[(long)bn*NROWS + bm*64 + tid] = M;
                psum[(long)bn*NROWS + bm*64 + tid] = S;
            }
        }
    }
}

// ---------------------------------------------------------------- K4:
// combine 125 partials per row -> lse -> masked NLL -> loss/N  (r = t*16+s)
__global__ __launch_bounds__(256) void reduce_loss(const float* __restrict__ pmax,
        const float* __restrict__ psum, const float* __restrict__ tlog,
        const int* __restrict__ captions, float* __restrict__ out){
    int r = blockIdx.x*256 + threadIdx.x;
    float M = -1e30f;
    for (int p=0;p<NVB;++p) M = fmaxf(M, pmax[(long)p*NROWS + r]);
    float S = 0.f;
    for (int p=0;p<NVB;++p) S += psum[(long)p*NROWS + r]*__expf(pmax[(long)p*NROWS + r]-M);
    float lse = M + logf(S);
    float nll = lse - tlog[r];
    int tok = captions[(r & 15)*257 + (r >> 4) + 1];
    float val = (tok != 0) ? nll : 0.f;
    __shared__ float red[256];
    red[threadIdx.x] = val; __syncthreads();
    for (int s=128; s>0; s>>=1){
        if (threadIdx.x < s) red[threadIdx.x] += red[threadIdx.x+s];
        __syncthreads();
    }
    if (threadIdx.x == 0) atomicAdd(out, red[0] * (1.0f/16.0f));
}

// ---------------------------------------------------------------- launch
extern "C" void kernel_launch(void* const* d_in, const int* in_sizes, int n_in,
                              void* d_out, int out_size, void* d_ws, size_t ws_size,
                              hipStream_t stream){
    const int*   captions = (const int*)  d_in[0];
    const float* Wemb     = (const float*)d_in[1];
    const float* Wx       = (const float*)d_in[2];
    const float* Wh       = (const float*)d_in[3];
    const float* b        = (const float*)d_in[4];
    const float* Wv       = (const float*)d_in[5];
    const float* bvoc     = (const float*)d_in[6];
    const float* h_init   = (const float*)d_in[7];

    char* ws = (char*)d_ws;
    float*          xw   = (float*)         (ws + 0);          // 33554432 B
    unsigned short* WvP  = (unsigned short*)(ws + 33554432);   // 32768000 B
    u64*            hsPq = (u64*)           (ws + 66322432);   //  4194304 B
    float*          pmax = (float*)         (ws + 70516736);   //  2048000 B
    float*          psum = (float*)         (ws + 72564736);   //  2048000 B
    float*          tlog = (float*)         (ws + 74612736);   //    16384 B
    unsigned short* Whp  = (unsigned short*)(ws + 74629120);   //  2097152 B
    u64*            hx   = (u64*)           (ws + 76726272);   //    65536 B (2 bufs x 4096 u64)
    int*            cnt  = (int*)           (ws + 76791808);   //     8192 B (64 x 128B lines)

    float* out_f = (float*)d_out;

    (void)hipMemsetAsync(d_out, 0, sizeof(float), stream);
    (void)hipMemsetAsync(cnt, 0, 8192, stream);

    hipLaunchKernelGGL(wv_pack,      dim3(500, 8), dim3(256), 0, stream, Wv, WvP);
    hipLaunchKernelGGL(whp_prep,     dim3(NWG),    dim3(256), 0, stream, Wh, Whp);
    hipLaunchKernelGGL(hg_init,      dim3(16),     dim3(256), 0, stream, h_init, hx);
    hipLaunchKernelGGL(embed_xw,     dim3(512),    dim3(256), 0, stream, captions, Wemb, Wx, b, xw);
    hipLaunchKernelGGL(fused_lstm_vocab, dim3(NWG + NWGEMM), dim3(256), 0, stream,
                       xw, Whp, hx, hsPq, cnt, WvP, bvoc, captions, pmax, psum, tlog);
    hipLaunchKernelGGL(reduce_loss,  dim3(16),     dim3(256), 0, stream, pmax, psum, tlog, captions, out_f);
}